// Round 1
// baseline (730.951 us; speedup 1.0000x reference)
//
#include <hip/hip_runtime.h>

// Problem: out[m, r] = sum_k values[k] * x[m, col_idx[k]] where row_ids[k]==r
//        == X[8192x4096] @ W^T, W[4096x4096] = scatter_add(values at (row,col))
// Strategy: scatter-add dense W (fp32 atomics), convert W and X to bf16,
// then m97-structure bf16 MFMA GEMM (C = A * B^T, both row-major [*,K]).

#define M_DIM 8192   // 4*2048 flattened batch rows
#define K_DIM 4096   // N_COLS
#define N_DIM 4096   // N_ROWS
#define NNZ   4194304

typedef __bf16 bf16x8 __attribute__((ext_vector_type(8)));
typedef float  floatx4 __attribute__((ext_vector_type(4)));

__device__ __forceinline__ unsigned short f32_to_bf16(float f) {
  unsigned int u = __float_as_uint(f);
  u += 0x7FFFu + ((u >> 16) & 1u);   // round-to-nearest-even
  return (unsigned short)(u >> 16);
}

__device__ __forceinline__ void async_copy16(const void* g, void* l) {
  __builtin_amdgcn_global_load_lds(
      (const __attribute__((address_space(1))) void*)g,
      (__attribute__((address_space(3))) void*)l,
      16, 0, 0);
}

__global__ void zero_kernel(float4* __restrict__ p, int n4) {
  int i = blockIdx.x * blockDim.x + threadIdx.x;
  if (i < n4) p[i] = make_float4(0.f, 0.f, 0.f, 0.f);
}

__global__ void scatter_kernel(const float* __restrict__ vals,
                               const int* __restrict__ cols,
                               const int* __restrict__ rows,
                               float* __restrict__ W) {
  int i = blockIdx.x * blockDim.x + threadIdx.x;
  if (i < NNZ) {
    // row_ids sorted -> consecutive threads touch the same 16KB W row: good locality
    atomicAdd(&W[(size_t)rows[i] * K_DIM + cols[i]], vals[i]);
  }
}

__global__ void cvt_kernel(const float4* __restrict__ in,
                           ushort4* __restrict__ out, int n4) {
  int i = blockIdx.x * blockDim.x + threadIdx.x;
  if (i < n4) {
    float4 v = in[i];
    ushort4 o;
    o.x = f32_to_bf16(v.x);
    o.y = f32_to_bf16(v.y);
    o.z = f32_to_bf16(v.z);
    o.w = f32_to_bf16(v.w);
    out[i] = o;
  }
}

// C[M,N] = A[M,K] * B[N,K]^T ; A,B bf16 row-major, C fp32 row-major.
// 128x128 tile, BK=32, 256 threads = 4 waves in 2x2, each wave 64x64 (4x4 MFMA tiles).
__global__ __launch_bounds__(256, 2) void gemm_bt(
    const unsigned short* __restrict__ A,
    const unsigned short* __restrict__ B,
    float* __restrict__ C) {
  // Unpadded [128][32] bf16 — required by global_load_lds contiguity (lane*16B).
  __shared__ unsigned short As[128 * 32];
  __shared__ unsigned short Bs[128 * 32];

  const int tid  = threadIdx.x;
  const int wave = tid >> 6;
  const int lane = tid & 63;
  const int quad = lane >> 4;
  const int l16  = lane & 15;

  const int m0 = blockIdx.y * 128;
  const int n0 = blockIdx.x * 128;

  const int wm = (wave >> 1) * 64;  // wave row offset in tile
  const int wn = (wave & 1) * 64;   // wave col offset in tile

  floatx4 acc[4][4];
#pragma unroll
  for (int i = 0; i < 4; i++)
#pragma unroll
    for (int j = 0; j < 4; j++) acc[i][j] = (floatx4){0.f, 0.f, 0.f, 0.f};

  // Staging: per instruction a wave covers 16 rows x 32 cols (64B/row, 4 lanes/row).
  const int srow = lane >> 2;       // 0..15
  const int scol = (lane & 3) * 8;  // k-element offset (16B chunks)

  const unsigned short* Ag0 = A + (size_t)(m0 +      wave * 16 + srow) * K_DIM + scol;
  const unsigned short* Ag1 = A + (size_t)(m0 + 64 + wave * 16 + srow) * K_DIM + scol;
  const unsigned short* Bg0 = B + (size_t)(n0 +      wave * 16 + srow) * K_DIM + scol;
  const unsigned short* Bg1 = B + (size_t)(n0 + 64 + wave * 16 + srow) * K_DIM + scol;

  // LDS dest = wave-uniform base + lane*16B (contiguous in lane order)
  unsigned short* Al0 = &As[(wave * 16) * 32] + lane * 8;
  unsigned short* Al1 = &As[(64 + wave * 16) * 32] + lane * 8;
  unsigned short* Bl0 = &Bs[(wave * 16) * 32] + lane * 8;
  unsigned short* Bl1 = &Bs[(64 + wave * 16) * 32] + lane * 8;

  for (int kt = 0; kt < K_DIM; kt += 32) {
    __syncthreads();  // protect LDS reuse (lgkm drain inserted by compiler)
    async_copy16(Ag0 + kt, Al0);
    async_copy16(Ag1 + kt, Al1);
    async_copy16(Bg0 + kt, Bl0);
    async_copy16(Bg1 + kt, Bl1);
    __syncthreads();  // vmcnt(0) drain inserted by compiler before barrier

    bf16x8 af[4], bf[4];
#pragma unroll
    for (int t = 0; t < 4; t++) {
      // A-operand: A[m=l16][k=quad*8+j] -> contiguous 16B ds_read_b128
      af[t] = *(const bf16x8*)&As[(wm + t * 16 + l16) * 32 + quad * 8];
      // B-operand: B[k=quad*8+j][n=l16] == W[n][k] row-major read
      bf[t] = *(const bf16x8*)&Bs[(wn + t * 16 + l16) * 32 + quad * 8];
    }
#pragma unroll
    for (int tm = 0; tm < 4; tm++)
#pragma unroll
      for (int tn = 0; tn < 4; tn++)
        acc[tm][tn] = __builtin_amdgcn_mfma_f32_16x16x32_bf16(
            af[tm], bf[tn], acc[tm][tn], 0, 0, 0);
  }

  // Epilogue: C/D layout col=lane&15, row=quad*4+reg  [measured m89/m91]
#pragma unroll
  for (int tm = 0; tm < 4; tm++) {
#pragma unroll
    for (int r = 0; r < 4; r++) {
      const int row = m0 + wm + tm * 16 + quad * 4 + r;
      float* Cp = C + (size_t)row * N_DIM + n0 + wn + l16;
#pragma unroll
      for (int tn = 0; tn < 4; tn++) Cp[tn * 16] = acc[tm][tn][r];
    }
  }
}

extern "C" void kernel_launch(void* const* d_in, const int* in_sizes, int n_in,
                              void* d_out, int out_size, void* d_ws, size_t ws_size,
                              hipStream_t stream) {
  const float* x       = (const float*)d_in[0];
  const float* values  = (const float*)d_in[1];
  const int*   col_idx = (const int*)d_in[2];
  const int*   row_ids = (const int*)d_in[3];
  float* out = (float*)d_out;

  // ws layout: [0,64MB) W fp32 | [64MB,96MB) W bf16 | [96MB,160MB) X bf16
  float* Wf          = (float*)d_ws;
  unsigned short* Wb = (unsigned short*)((char*)d_ws + ((size_t)64 << 20));
  unsigned short* Xb = (unsigned short*)((char*)d_ws + ((size_t)96 << 20));

  const int w4 = N_DIM * K_DIM / 4;  // 4M float4
  const int x4 = M_DIM * K_DIM / 4;  // 8M float4

  zero_kernel<<<(w4 + 255) / 256, 256, 0, stream>>>((float4*)Wf, w4);
  scatter_kernel<<<(NNZ + 255) / 256, 256, 0, stream>>>(values, col_idx, row_ids, Wf);
  cvt_kernel<<<(w4 + 255) / 256, 256, 0, stream>>>((const float4*)Wf, (ushort4*)Wb, w4);
  cvt_kernel<<<(x4 + 255) / 256, 256, 0, stream>>>((const float4*)x, (ushort4*)Xb, x4);

  dim3 grid(N_DIM / 128, M_DIM / 128);  // (32, 64) = 2048 blocks
  gemm_bt<<<grid, 256, 0, stream>>>(Xb, Wb, out);
}

// Round 2
// 577.839 us; speedup vs baseline: 1.2650x; 1.2650x over previous
//
#include <hip/hip_runtime.h>

// Problem: out[m, r] = sum_k values[k] * x[m, col_idx[k]] where row_ids[k]==r
//        == X[8192x4096] @ W^T, W[4096x4096] = scatter_add(values at (row,col))
// R2: row_ids is SORTED -> build each dense W row in LDS (16KB fp32), LDS
// atomics, emit bf16 directly. Kills zero+global-scatter+W-cvt (was ~395us).

#define M_DIM 8192   // 4*2048 flattened batch rows
#define K_DIM 4096   // N_COLS
#define N_DIM 4096   // N_ROWS
#define NNZ   4194304

typedef __bf16 bf16x8 __attribute__((ext_vector_type(8)));
typedef float  floatx4 __attribute__((ext_vector_type(4)));
typedef unsigned short ushort8 __attribute__((ext_vector_type(8)));

__device__ __forceinline__ unsigned short f32_to_bf16(float f) {
  unsigned int u = __float_as_uint(f);
  u += 0x7FFFu + ((u >> 16) & 1u);   // round-to-nearest-even
  return (unsigned short)(u >> 16);
}

__device__ __forceinline__ void async_copy16(const void* g, void* l) {
  __builtin_amdgcn_global_load_lds(
      (const __attribute__((address_space(1))) void*)g,
      (__attribute__((address_space(3))) void*)l,
      16, 0, 0);
}

// One block per W row. Segment [start,end) of the sorted row_ids found by
// binary search; accumulate into a 16KB LDS row with LDS atomics; write bf16.
__global__ __launch_bounds__(256) void build_w_kernel(
    const float* __restrict__ vals,
    const int* __restrict__ cols,
    const int* __restrict__ rows,
    unsigned short* __restrict__ Wb) {
  __shared__ float wrow[K_DIM];  // 16KB

  const int r = blockIdx.x;
  for (int i = threadIdx.x; i < K_DIM; i += 256) wrow[i] = 0.f;
  __syncthreads();

  // lower_bound(rows, r) and lower_bound(rows, r+1); wave-uniform, L2-cached.
  int lo = 0, hi = NNZ;
  while (lo < hi) { int mid = (lo + hi) >> 1; if (rows[mid] < r) lo = mid + 1; else hi = mid; }
  const int start = lo;
  hi = NNZ;
  while (lo < hi) { int mid = (lo + hi) >> 1; if (rows[mid] < r + 1) lo = mid + 1; else hi = mid; }
  const int end = lo;

  for (int i = start + threadIdx.x; i < end; i += 256)
    atomicAdd(&wrow[cols[i]], vals[i]);   // LDS atomic: no L2 RMW
  __syncthreads();

  // Emit the bf16 row: 512 x 8-elem chunks, 16B stores.
  ushort8* dst = (ushort8*)(Wb + (size_t)r * K_DIM);
  for (int i = threadIdx.x; i < K_DIM / 8; i += 256) {
    const float* s = &wrow[i * 8];
    ushort8 o;
#pragma unroll
    for (int j = 0; j < 8; j++) o[j] = f32_to_bf16(s[j]);
    dst[i] = o;
  }
}

__global__ void cvt_kernel(const float4* __restrict__ in,
                           ushort4* __restrict__ out, int n4) {
  int i = blockIdx.x * blockDim.x + threadIdx.x;
  if (i < n4) {
    float4 v = in[i];
    ushort4 o;
    o.x = f32_to_bf16(v.x);
    o.y = f32_to_bf16(v.y);
    o.z = f32_to_bf16(v.z);
    o.w = f32_to_bf16(v.w);
    out[i] = o;
  }
}

// C[M,N] = A[M,K] * B[N,K]^T ; A,B bf16 row-major, C fp32 row-major.
// 128x128 tile, BK=32, 256 threads = 4 waves in 2x2, each wave 64x64 (4x4 MFMA tiles).
__global__ __launch_bounds__(256, 2) void gemm_bt(
    const unsigned short* __restrict__ A,
    const unsigned short* __restrict__ B,
    float* __restrict__ C) {
  // Unpadded [128][32] bf16 — required by global_load_lds contiguity (lane*16B).
  __shared__ unsigned short As[128 * 32];
  __shared__ unsigned short Bs[128 * 32];

  const int tid  = threadIdx.x;
  const int wave = tid >> 6;
  const int lane = tid & 63;
  const int quad = lane >> 4;
  const int l16  = lane & 15;

  const int m0 = blockIdx.y * 128;
  const int n0 = blockIdx.x * 128;

  const int wm = (wave >> 1) * 64;  // wave row offset in tile
  const int wn = (wave & 1) * 64;   // wave col offset in tile

  floatx4 acc[4][4];
#pragma unroll
  for (int i = 0; i < 4; i++)
#pragma unroll
    for (int j = 0; j < 4; j++) acc[i][j] = (floatx4){0.f, 0.f, 0.f, 0.f};

  // Staging: per instruction a wave covers 16 rows x 32 cols (64B/row, 4 lanes/row).
  const int srow = lane >> 2;       // 0..15
  const int scol = (lane & 3) * 8;  // k-element offset (16B chunks)

  const unsigned short* Ag0 = A + (size_t)(m0 +      wave * 16 + srow) * K_DIM + scol;
  const unsigned short* Ag1 = A + (size_t)(m0 + 64 + wave * 16 + srow) * K_DIM + scol;
  const unsigned short* Bg0 = B + (size_t)(n0 +      wave * 16 + srow) * K_DIM + scol;
  const unsigned short* Bg1 = B + (size_t)(n0 + 64 + wave * 16 + srow) * K_DIM + scol;

  // LDS dest = wave-uniform base + lane*16B (contiguous in lane order)
  unsigned short* Al0 = &As[(wave * 16) * 32] + lane * 8;
  unsigned short* Al1 = &As[(64 + wave * 16) * 32] + lane * 8;
  unsigned short* Bl0 = &Bs[(wave * 16) * 32] + lane * 8;
  unsigned short* Bl1 = &Bs[(64 + wave * 16) * 32] + lane * 8;

  for (int kt = 0; kt < K_DIM; kt += 32) {
    __syncthreads();  // protect LDS reuse (lgkm drain inserted by compiler)
    async_copy16(Ag0 + kt, Al0);
    async_copy16(Ag1 + kt, Al1);
    async_copy16(Bg0 + kt, Bl0);
    async_copy16(Bg1 + kt, Bl1);
    __syncthreads();  // vmcnt(0) drain inserted by compiler before barrier

    bf16x8 af[4], bf[4];
#pragma unroll
    for (int t = 0; t < 4; t++) {
      // A-operand: A[m=l16][k=quad*8+j] -> contiguous 16B ds_read_b128
      af[t] = *(const bf16x8*)&As[(wm + t * 16 + l16) * 32 + quad * 8];
      // B-operand: B[k=quad*8+j][n=l16] == W[n][k] row-major read
      bf[t] = *(const bf16x8*)&Bs[(wn + t * 16 + l16) * 32 + quad * 8];
    }
#pragma unroll
    for (int tm = 0; tm < 4; tm++)
#pragma unroll
      for (int tn = 0; tn < 4; tn++)
        acc[tm][tn] = __builtin_amdgcn_mfma_f32_16x16x32_bf16(
            af[tm], bf[tn], acc[tm][tn], 0, 0, 0);
  }

  // Epilogue: C/D layout col=lane&15, row=quad*4+reg  [measured m89/m91]
#pragma unroll
  for (int tm = 0; tm < 4; tm++) {
#pragma unroll
    for (int r = 0; r < 4; r++) {
      const int row = m0 + wm + tm * 16 + quad * 4 + r;
      float* Cp = C + (size_t)row * N_DIM + n0 + wn + l16;
#pragma unroll
      for (int tn = 0; tn < 4; tn++) Cp[tn * 16] = acc[tm][tn][r];
    }
  }
}

extern "C" void kernel_launch(void* const* d_in, const int* in_sizes, int n_in,
                              void* d_out, int out_size, void* d_ws, size_t ws_size,
                              hipStream_t stream) {
  const float* x       = (const float*)d_in[0];
  const float* values  = (const float*)d_in[1];
  const int*   col_idx = (const int*)d_in[2];
  const int*   row_ids = (const int*)d_in[3];
  float* out = (float*)d_out;

  // ws layout: [0,32MB) W bf16 | [32MB,96MB) X bf16
  unsigned short* Wb = (unsigned short*)d_ws;
  unsigned short* Xb = (unsigned short*)((char*)d_ws + ((size_t)32 << 20));

  const int x4 = M_DIM * K_DIM / 4;  // 8M float4

  build_w_kernel<<<N_DIM, 256, 0, stream>>>(values, col_idx, row_ids, Wb);
  cvt_kernel<<<(x4 + 255) / 256, 256, 0, stream>>>((const float4*)x, (ushort4*)Xb, x4);

  dim3 grid(N_DIM / 128, M_DIM / 128);  // (32, 64) = 2048 blocks
  gemm_bt<<<grid, 256, 0, stream>>>(Xb, Wb, out);
}

// Round 3
// 547.807 us; speedup vs baseline: 1.3343x; 1.0548x over previous
//
#include <hip/hip_runtime.h>

// out = X[8192x4096] @ W^T, W[4096x4096] = scatter_add(values at (row,col)), row_ids sorted.
// R3: (a) fixed-point int LDS atomics (native ds_add_u32; fp32 atomicAdd lowers to a
// CAS loop without -munsafe-fp-atomics — suspected R1/R2 preproc cost);
// (b) precomputed row_start table replaces per-block binary search.

#define M_DIM 8192
#define K_DIM 4096
#define N_DIM 4096
#define NNZ   4194304
#define FXSCALE 1048576.0f          // 2^20 fixed-point scale
#define FXINV  (1.0f / 1048576.0f)

typedef __bf16 bf16x8 __attribute__((ext_vector_type(8)));
typedef float  floatx4 __attribute__((ext_vector_type(4)));
typedef unsigned short ushort8 __attribute__((ext_vector_type(8)));

__device__ __forceinline__ unsigned short f32_to_bf16(float f) {
  unsigned int u = __float_as_uint(f);
  u += 0x7FFFu + ((u >> 16) & 1u);   // round-to-nearest-even
  return (unsigned short)(u >> 16);
}

__device__ __forceinline__ void async_copy16(const void* g, void* l) {
  __builtin_amdgcn_global_load_lds(
      (const __attribute__((address_space(1))) void*)g,
      (__attribute__((address_space(3))) void*)l,
      16, 0, 0);
}

// row_start[r] = lower_bound(rows, r); covers r in [0, N_DIM] exactly once.
__global__ void row_start_kernel(const int* __restrict__ rows,
                                 int* __restrict__ row_start) {
  int i = blockIdx.x * blockDim.x + threadIdx.x;
  if (i > NNZ) return;
  int cur  = (i < NNZ) ? rows[i] : N_DIM;
  int prev = (i > 0) ? rows[i - 1] : -1;
  for (int r = prev + 1; r <= cur; ++r) row_start[r] = i;
}

// One block per W row: dense row in LDS as 2^20 fixed-point ints (native
// ds_add_u32 atomics), then emit bf16.
__global__ __launch_bounds__(256) void build_w_kernel(
    const float* __restrict__ vals,
    const int* __restrict__ cols,
    const int* __restrict__ row_start,
    unsigned short* __restrict__ Wb) {
  __shared__ int wrow[K_DIM];  // 16KB

  const int r = blockIdx.x;
  for (int i = threadIdx.x; i < K_DIM; i += 256) wrow[i] = 0;
  __syncthreads();

  const int start = row_start[r];
  const int end   = row_start[r + 1];
  for (int i = start + threadIdx.x; i < end; i += 256)
    atomicAdd(&wrow[cols[i]], (int)lrintf(vals[i] * FXSCALE));
  __syncthreads();

  ushort8* dst = (ushort8*)(Wb + (size_t)r * K_DIM);
  for (int i = threadIdx.x; i < K_DIM / 8; i += 256) {
    const int* s = &wrow[i * 8];
    ushort8 o;
#pragma unroll
    for (int j = 0; j < 8; j++) o[j] = f32_to_bf16((float)s[j] * FXINV);
    dst[i] = o;
  }
}

__global__ void cvt_kernel(const float4* __restrict__ in,
                           ushort4* __restrict__ out, int n4) {
  int i = blockIdx.x * blockDim.x + threadIdx.x;
  if (i < n4) {
    float4 v = in[i];
    ushort4 o;
    o.x = f32_to_bf16(v.x);
    o.y = f32_to_bf16(v.y);
    o.z = f32_to_bf16(v.z);
    o.w = f32_to_bf16(v.w);
    out[i] = o;
  }
}

// C[M,N] = A[M,K] * B[N,K]^T ; unchanged m97-structure GEMM (328us, MfmaUtil 37%).
__global__ __launch_bounds__(256, 2) void gemm_bt(
    const unsigned short* __restrict__ A,
    const unsigned short* __restrict__ B,
    float* __restrict__ C) {
  __shared__ unsigned short As[128 * 32];
  __shared__ unsigned short Bs[128 * 32];

  const int tid  = threadIdx.x;
  const int wave = tid >> 6;
  const int lane = tid & 63;
  const int quad = lane >> 4;
  const int l16  = lane & 15;

  const int m0 = blockIdx.y * 128;
  const int n0 = blockIdx.x * 128;

  const int wm = (wave >> 1) * 64;
  const int wn = (wave & 1) * 64;

  floatx4 acc[4][4];
#pragma unroll
  for (int i = 0; i < 4; i++)
#pragma unroll
    for (int j = 0; j < 4; j++) acc[i][j] = (floatx4){0.f, 0.f, 0.f, 0.f};

  const int srow = lane >> 2;
  const int scol = (lane & 3) * 8;

  const unsigned short* Ag0 = A + (size_t)(m0 +      wave * 16 + srow) * K_DIM + scol;
  const unsigned short* Ag1 = A + (size_t)(m0 + 64 + wave * 16 + srow) * K_DIM + scol;
  const unsigned short* Bg0 = B + (size_t)(n0 +      wave * 16 + srow) * K_DIM + scol;
  const unsigned short* Bg1 = B + (size_t)(n0 + 64 + wave * 16 + srow) * K_DIM + scol;

  unsigned short* Al0 = &As[(wave * 16) * 32] + lane * 8;
  unsigned short* Al1 = &As[(64 + wave * 16) * 32] + lane * 8;
  unsigned short* Bl0 = &Bs[(wave * 16) * 32] + lane * 8;
  unsigned short* Bl1 = &Bs[(64 + wave * 16) * 32] + lane * 8;

  for (int kt = 0; kt < K_DIM; kt += 32) {
    __syncthreads();
    async_copy16(Ag0 + kt, Al0);
    async_copy16(Ag1 + kt, Al1);
    async_copy16(Bg0 + kt, Bl0);
    async_copy16(Bg1 + kt, Bl1);
    __syncthreads();

    bf16x8 af[4], bf[4];
#pragma unroll
    for (int t = 0; t < 4; t++) {
      af[t] = *(const bf16x8*)&As[(wm + t * 16 + l16) * 32 + quad * 8];
      bf[t] = *(const bf16x8*)&Bs[(wn + t * 16 + l16) * 32 + quad * 8];
    }
#pragma unroll
    for (int tm = 0; tm < 4; tm++)
#pragma unroll
      for (int tn = 0; tn < 4; tn++)
        acc[tm][tn] = __builtin_amdgcn_mfma_f32_16x16x32_bf16(
            af[tm], bf[tn], acc[tm][tn], 0, 0, 0);
  }

#pragma unroll
  for (int tm = 0; tm < 4; tm++) {
#pragma unroll
    for (int r = 0; r < 4; r++) {
      const int row = m0 + wm + tm * 16 + quad * 4 + r;
      float* Cp = C + (size_t)row * N_DIM + n0 + wn + l16;
#pragma unroll
      for (int tn = 0; tn < 4; tn++) Cp[tn * 16] = acc[tm][tn][r];
    }
  }
}

extern "C" void kernel_launch(void* const* d_in, const int* in_sizes, int n_in,
                              void* d_out, int out_size, void* d_ws, size_t ws_size,
                              hipStream_t stream) {
  const float* x       = (const float*)d_in[0];
  const float* values  = (const float*)d_in[1];
  const int*   col_idx = (const int*)d_in[2];
  const int*   row_ids = (const int*)d_in[3];
  float* out = (float*)d_out;

  // ws layout: [0,32MB) W bf16 | [32MB,96MB) X bf16 | [96MB,+16.4KB) row_start
  unsigned short* Wb = (unsigned short*)d_ws;
  unsigned short* Xb = (unsigned short*)((char*)d_ws + ((size_t)32 << 20));
  int* row_start     = (int*)((char*)d_ws + ((size_t)96 << 20));

  const int x4 = M_DIM * K_DIM / 4;

  row_start_kernel<<<(NNZ + 256) / 256, 256, 0, stream>>>(row_ids, row_start);
  cvt_kernel<<<(x4 + 255) / 256, 256, 0, stream>>>((const float4*)x, (ushort4*)Xb, x4);
  build_w_kernel<<<N_DIM, 256, 0, stream>>>(values, col_idx, row_start, Wb);

  dim3 grid(N_DIM / 128, M_DIM / 128);  // (32, 64)
  gemm_bt<<<grid, 256, 0, stream>>>(Xb, Wb, out);
}